// Round 14
// baseline (75.288 us; speedup 1.0000x reference)
//
#include <hip/hip_runtime.h>

#define T_ 64
#define B_ 32
#define P_ 32
#define N_ 1024
#define H_ 128
#define G_ 512   // 4*H

typedef __attribute__((ext_vector_type(8))) _Float16 half8;
typedef __attribute__((ext_vector_type(4))) float f32x4;

__device__ __forceinline__ float rcpf(float x){ return __builtin_amdgcn_rcpf(x); }
__device__ __forceinline__ float sigm(float x){ return rcpf(1.f+__expf(-x)); }
__device__ __forceinline__ float tanh_fast(float x){ return 1.f - 2.f*rcpf(__expf(2.f*x)+1.f); }

// ---------------- Kernel 0: prep (32 blocks) ----------------
// blk 0-7 : Bx fragments (x-projection fold + bias hi/lo as k-slots)
// blk 8-31: F1/F2/A1 B-fragment builders (8 n-tiles each), f16
__global__ __launch_bounds__(256) void prep_kernel(
    const float* __restrict__ W_sp, const float* __restrict__ b_sp,
    const float* __restrict__ W_st, const float* __restrict__ b_st,
    const float* __restrict__ Wih_t, const float* __restrict__ bih_t,
    const float* __restrict__ bhh_t,
    const float* __restrict__ Wih_s, const float* __restrict__ bih_s,
    const float* __restrict__ bhh_s,
    const float* __restrict__ F1, const float* __restrict__ F2,
    const float* __restrict__ A1,
    _Float16* __restrict__ Bxfrag,
    _Float16* __restrict__ F1frag, _Float16* __restrict__ F2frag,
    _Float16* __restrict__ A1frag)
{
  __shared__ float Wl[128][129];       // 66KB staging
  __shared__ float spw[512];
  __shared__ float bsm[128];
  __shared__ float prt[128][8];

  const int tid = threadIdx.x;
  const int blk = blockIdx.x;

  if (blk < 8) {
    const int L = blk >> 2, q = blk & 3;
    const int g0 = q*128;
    const float* Wih = L ? Wih_s : Wih_t;
    {
      unsigned int* Bz = (unsigned int*)Bxfrag;
      for (int i = tid; i < 2048; i += 256){
        const int wv = i >> 8, word = i & 255;
        Bz[((L*8+wv)*4+q)*256 + word] = 0u;
      }
    }
    if (L == 0){
      if (tid < 256) spw[tid] = W_sp[tid];
      if (tid < 128) bsm[tid] = b_sp[tid];
    } else {
      spw[tid] = W_st[tid]; spw[256+tid] = W_st[256+tid];
      if (tid < 128) bsm[tid] = b_st[tid];
    }
    for (int idx = tid; idx < 4096; idx += 256){
      const int r = idx >> 5, c4 = idx & 31;
      const float4 v = *(const float4*)(Wih + (size_t)(g0+r)*H_ + c4*4);
      Wl[r][c4*4+0]=v.x; Wl[r][c4*4+1]=v.y; Wl[r][c4*4+2]=v.z; Wl[r][c4*4+3]=v.w;
    }
    __syncthreads();
    const int g_l = tid & 127, half = tid >> 7, e0 = half*64;
    float a0=0.f,a1v=0.f,a2=0.f,a3=0.f,ab=0.f;
    if (L == 0){
      for (int e=e0; e<e0+64; ++e){
        const float wv = Wl[g_l][e];
        a0 += wv*spw[e*2]; a1v += wv*spw[e*2+1]; ab += wv*bsm[e];
      }
    } else {
      for (int e=e0; e<e0+64; ++e){
        const float wv = Wl[g_l][e];
        a0 += wv*spw[e*4]; a1v += wv*spw[e*4+1]; a2 += wv*spw[e*4+2]; a3 += wv*spw[e*4+3];
        ab += wv*bsm[e];
      }
    }
    if (half == 1){ prt[g_l][0]=a0; prt[g_l][1]=a1v; prt[g_l][2]=a2; prt[g_l][3]=a3; prt[g_l][4]=ab; }
    __syncthreads();
    if (half == 0){
      a0 += prt[g_l][0]; a1v += prt[g_l][1]; a2 += prt[g_l][2]; a3 += prt[g_l][3]; ab += prt[g_l][4];
      const int g = g0 + g_l;
      const float bsum = ab + (L ? bih_s[g] : bih_t[g]) + (L ? bhh_s[g] : bhh_t[g]);
      const int wv = g_l >> 4, lane = g_l & 15;
      _Float16* dst = Bxfrag + (size_t)(((L*8+wv)*4+q)*64 + lane)*8;
      if (L == 0){
        dst[0]=(_Float16)a0; dst[1]=(_Float16)a1v; dst[2]=(_Float16)0.f; dst[3]=(_Float16)0.f;
      } else {
        dst[0]=(_Float16)a0; dst[1]=(_Float16)a1v; dst[2]=(_Float16)a2; dst[3]=(_Float16)a3;
      }
      const _Float16 bh = (_Float16)bsum;
      dst[4]=bh; dst[5]=(_Float16)(bsum-(float)bh);
    }
  } else {
    // B-fragment builders for head matrices
    const int fb = blk - 8;             // 0..23
    const int btype = fb >> 3;          // 0=F1, 1=F2, 2=A1
    const int nt = fb & 7;
    const float* src = (btype==0) ? F1 : (btype==1) ? F2 : A1;
    _Float16* dstf   = (btype==0) ? F1frag : (btype==1) ? F2frag : A1frag;
    const int K = (btype==1) ? 128 : 256;
    float* S = &Wl[0][0];               // staging, stride 257
    const int nf4 = 16*K/4;
    for (int i = tid; i < nf4; i += 256){
      const int r = i / (K/4), c4 = i % (K/4);
      const float4 v = *(const float4*)(src + (size_t)(nt*16+r)*K + c4*4);
      S[r*257 + c4*4+0]=v.x; S[r*257 + c4*4+1]=v.y;
      S[r*257 + c4*4+2]=v.z; S[r*257 + c4*4+3]=v.w;
    }
    __syncthreads();
    const int nkt = K/32;
    for (int s = tid; s < nkt*64; s += 256){
      const int kt = s >> 6, l = s & 63;
      half8 v;
      #pragma unroll
      for (int jj=0;jj<8;jj++)
        v[jj] = (_Float16)S[(l&15)*257 + kt*32 + 8*(l>>4) + jj];
      *(half8*)(dstf + (size_t)((nt*nkt + kt)*64 + l)*8) = v;
    }
  }
}

// ---------------- Kernel 1: both masked LSTMs, MFMA ----------------
// B weight fragments gathered directly from global Whh at startup (L2-hot,
// one-time; replaces the 64-block Wfrag prep + workspace round-trip).
__global__ __launch_bounds__(512) __attribute__((amdgpu_waves_per_eu(2,2)))
void lstm_kernel(
    const float* __restrict__ rel, const float* __restrict__ pvx,
    const float* __restrict__ pvy, const float* __restrict__ pax,
    const float* __restrict__ pay, const int* __restrict__ maskI,
    const float* __restrict__ Whh_t, const float* __restrict__ Whh_s,
    const _Float16* __restrict__ Bxfrag,
    float* __restrict__ h_t_out, float* __restrict__ h_s_out)
{
  __shared__ _Float16 hA[2][4][64][8] __align__(16);   // h f16, dbuf, 8KB
  __shared__ _Float16 axf[T_][16][8] __align__(16);    // x A-frags, 16KB
  __shared__ _Float16 zslot[8] __align__(16);
  __shared__ unsigned int ml[T_];

  const int lstm = blockIdx.y;
  const int tid  = threadIdx.x;
  const int w    = tid >> 6;
  const int l    = tid & 63;
  const int n0   = blockIdx.x * 8;
  const int u    = w*16 + (l & 15);
  const int kt_u = u >> 5;

  const float* Whh = lstm ? Whh_s : Whh_t;

  // ---- gather B fragments from global Whh (f32 -> f16), + bx from Bxfrag ----
  half8 bw[4][4], bx[4];
  #pragma unroll
  for (int n=0;n<4;n++){
    #pragma unroll
    for (int t=0;t<4;t++){
      const size_t base = (size_t)(n*128 + w*16 + (l & 15))*H_ + t*32 + 8*(l>>4);
      const float4 v0 = *(const float4*)(Whh + base);
      const float4 v1 = *(const float4*)(Whh + base + 4);
      half8 v;
      v[0]=(_Float16)v0.x; v[1]=(_Float16)v0.y; v[2]=(_Float16)v0.z; v[3]=(_Float16)v0.w;
      v[4]=(_Float16)v1.x; v[5]=(_Float16)v1.y; v[6]=(_Float16)v1.z; v[7]=(_Float16)v1.w;
      bw[n][t] = v;
    }
    bx[n] = *(const half8*)(Bxfrag + (((lstm*8 + w)*4 + n)*64 + l)*8);
  }

  {
    const int t = tid >> 3, r = tid & 7;
    const int n = n0 + r, b = n >> 5, p = n & 31;
    float x0,x1,x2,x3;
    if (lstm == 0){
      x0 = rel[(t*B_+b)*64 + p]; x1 = rel[(t*B_+b)*64 + 32 + p];
      x2 = 0.f; x3 = 0.f;
    } else {
      const int i0 = t*N_ + n;
      x0 = pvx[i0]; x1 = pvy[i0]; x2 = pax[i0]; x3 = pay[i0];
    }
    half8 v;
    v[0]=(_Float16)x0; v[1]=(_Float16)x1; v[2]=(_Float16)x2; v[3]=(_Float16)x3;
    v[4]=(_Float16)1.f; v[5]=(_Float16)1.f; v[6]=(_Float16)0.f; v[7]=(_Float16)0.f;
    *(half8*)&axf[t][r][0] = v;
    half8 zz;
    #pragma unroll
    for (int q=0;q<8;q++) zz[q]=(_Float16)0.f;
    *(half8*)&axf[t][8+r][0] = zz;
    if (tid == 0) *(half8*)&zslot[0] = zz;
    if (tid < T_){
      unsigned int mw = 0;
      for (int rr=0; rr<8; rr++) mw |= (maskI[tid*N_ + n0 + rr] > 0) ? (1u<<rr) : 0u;
      ml[tid] = mw;
    }
  }
  {
    unsigned int* hz = (unsigned int*)&hA[0][0][0][0];
    #pragma unroll
    for (int i=0;i<4;i++) hz[tid + i*512] = 0u;
  }

  const int halfw = l >> 5;
  const int rbase = ((l & 31) >> 4)*4 + 2*halfw;
  const int lpp0  = rbase + 16*((u >> 3) & 3);
  const int hoff0 = kt_u*512 + lpp0*8 + (u & 7);
  const int hoff1 = hoff0 + 8;
  _Float16* hbase = &hA[0][0][0][0];
  const _Float16* axp_base = (l < 16) ? &axf[0][l][0] : &zslot[0];
  const int ax_stride = (l < 16) ? 128 : 0;

  float cc0 = 0.f, cc1 = 0.f;
  _Float16 rh0 = (_Float16)0.f, rh1 = (_Float16)0.f;
  __syncthreads();

  const f32x4 zc = {0.f, 0.f, 0.f, 0.f};
  #pragma unroll 2
  for (int t=0; t<T_; ++t){
    const int cur = t & 1, nxt = cur ^ 1;
    const unsigned int mw = ml[t];

    const half8 ax = *(const half8*)(axp_base + t*ax_stride);
    f32x4 acc[4];
    #pragma unroll
    for (int n=0;n<4;n++)
      acc[n] = __builtin_amdgcn_mfma_f32_16x16x32_f16(ax, bx[n], zc, 0, 0, 0);

    half8 ah[4];
    #pragma unroll
    for (int kt=0;kt<4;kt++) ah[kt] = *(const half8*)&hA[cur][kt][l][0];

    #pragma unroll
    for (int kt=0;kt<4;kt++)
      #pragma unroll
      for (int n=0;n<4;n++)
        acc[n] = __builtin_amdgcn_mfma_f32_16x16x32_f16(ah[kt], bw[n][kt], acc[n], 0, 0, 0);

    float g0[4], g1[4];
    #pragma unroll
    for (int n=0;n<4;n++){
      const float s2 = __shfl_xor(acc[n][2], 32, 64);
      const float s3 = __shfl_xor(acc[n][3], 32, 64);
      g0[n] = halfw ? s2 : acc[n][0];
      g1[n] = halfw ? s3 : acc[n][1];
    }

    {
      const float cn = sigm(g0[1])*cc0 + sigm(g0[0])*tanh_fast(g0[2]);
      const float hn = sigm(g0[3])*tanh_fast(cn);
      const int mb = (mw >> rbase) & 1;
      cc0 = mb ? cn : cc0;
      rh0 = mb ? (_Float16)hn : rh0;
      hbase[nxt*2048 + hoff0] = rh0;
    }
    {
      const float cn = sigm(g1[1])*cc1 + sigm(g1[0])*tanh_fast(g1[2]);
      const float hn = sigm(g1[3])*tanh_fast(cn);
      const int mb = (mw >> (rbase+1)) & 1;
      cc1 = mb ? cn : cc1;
      rh1 = mb ? (_Float16)hn : rh1;
      hbase[nxt*2048 + hoff1] = rh1;
    }
    __syncthreads();
  }

  float* hout = lstm ? h_s_out : h_t_out;
  hout[(n0 + rbase    )*H_ + u] = (float)rh0;
  hout[(n0 + rbase + 1)*H_ + u] = (float)rh1;
}

// ---------------- Kernel 2: MFMA head (unchanged from R13) ----------------
__global__ __launch_bounds__(512) void head_kernel(
    const float* __restrict__ h_t, const float* __restrict__ h_s,
    const int* __restrict__ maskI,
    const _Float16* __restrict__ F1frag, const float* __restrict__ f1,
    const _Float16* __restrict__ F2frag, const float* __restrict__ f2,
    const _Float16* __restrict__ A1frag, const float* __restrict__ a1,
    const float* __restrict__ A2, const float* __restrict__ a2v,
    float* __restrict__ out)
{
  extern __shared__ char hsm[];
  _Float16* combf = (_Float16*)hsm;              // [2m][2hl][8kt][64][8] 32768B
  _Float16* fusf  = (_Float16*)hsm;              // alias: [2m][2hl][4kt][64][8] 16384B
  _Float16* hidf  = (_Float16*)(hsm + 32768);    // [2m][2hl][4kt][64][8] 16384B
  float* fus      = (float*)(hsm + 49152);       // [32][129] 16512B
  float* meansh   = (float*)(hsm + 65664);       // 128
  float* okcnt    = (float*)(hsm + 66176);       // 512
  float* okv      = (float*)(hsm + 68224);       // 32
  float* sred     = (float*)(hsm + 68352);       // 32x4
  float* wgt      = (float*)(hsm + 68864);       // 32
  float* part     = (float*)(hsm + 68992);       // 4x128
  float* nvp      = (float*)(hsm + 71040);       // 1

  const int b = blockIdx.x, tid = threadIdx.x;
  const int w = tid >> 6, l = tid & 63;
  const int m = w >> 2;
  const int n0 = (w & 3) * 2;
  const int ccol = l & 15;

  #pragma unroll
  for (int it = 0; it < 4; ++it){
    const int slot = tid + it*512;
    const int r = slot >> 6, c4 = slot & 63;
    const float4 v = (c4 < 32)
      ? *(const float4*)(h_t + (size_t)(b*P_+r)*H_ + c4*4)
      : *(const float4*)(h_s + (size_t)(b*P_+r)*H_ + (c4-32)*4);
    const int mm = r >> 4, rl = r & 15;
    float vv[4] = {v.x, v.y, v.z, v.w};
    #pragma unroll
    for (int e=0;e<4;e++){
      const int k = c4*4 + e;
      const int lane = rl + 16*((k>>3)&3);
      const int jj = k & 7, kt = k >> 5;
      const _Float16 hi = (_Float16)vv[e];
      const _Float16 lo = (_Float16)(vv[e] - (float)hi);
      combf[(size_t)((mm*2+0)*8+kt)*512 + lane*8 + jj] = hi;
      combf[(size_t)((mm*2+1)*8+kt)*512 + lane*8 + jj] = lo;
    }
  }
  {
    const int p = tid >> 4, tt = tid & 15;
    int c = 0;
    #pragma unroll
    for (int q2=0;q2<4;q2++) c += (maskI[(tt*4+q2)*N_ + b*P_ + p] > 0);
    okcnt[p*16+tt] = (float)c;
  }
  __syncthreads();

  if (tid < 32){
    float c = 0.f;
    #pragma unroll
    for (int q2=0;q2<16;q2++) c += okcnt[tid*16+q2];
    const float ok = (c >= 2.f) ? 1.f : 0.f;
    okv[tid] = ok;
    float nvv = ok;
    #pragma unroll
    for (int off=16; off>=1; off>>=1) nvv += __shfl_xor(nvv, off, 32);
    if (tid == 0) nvp[0] = fmaxf(nvv, 1.f);
  }

  const f32x4 zc = {0.f,0.f,0.f,0.f};

  // ---- F1 ----
  half8 ah[8], al[8];
  #pragma unroll
  for (int kt=0;kt<8;kt++){
    ah[kt] = *(const half8*)(combf + (size_t)((m*2+0)*8+kt)*512 + l*8);
    al[kt] = *(const half8*)(combf + (size_t)((m*2+1)*8+kt)*512 + l*8);
  }
  float hval[2][4];
  #pragma unroll
  for (int t2=0;t2<2;t2++){
    const int nt = n0 + t2;
    f32x4 acc = zc;
    #pragma unroll
    for (int kt=0;kt<8;kt++){
      const half8 bb = *(const half8*)(F1frag + (size_t)((nt*8+kt)*64 + l)*8);
      acc = __builtin_amdgcn_mfma_f32_16x16x32_f16(ah[kt], bb, acc, 0, 0, 0);
      acc = __builtin_amdgcn_mfma_f32_16x16x32_f16(al[kt], bb, acc, 0, 0, 0);
    }
    const float bias = f1[nt*16 + ccol];
    #pragma unroll
    for (int reg=0;reg<4;reg++) hval[t2][reg] = fmaxf(acc[reg] + bias, 0.f);
  }
  #pragma unroll
  for (int t2=0;t2<2;t2++){
    const int jb = (n0+t2)*16 + ccol;
    const int kt2 = jb >> 5, lgrp = 16*((jb>>3)&3), jj2 = jb & 7;
    #pragma unroll
    for (int reg=0;reg<4;reg++){
      const int row = (l>>4)*4 + reg;
      const float hv2 = hval[t2][reg];
      const _Float16 hi = (_Float16)hv2;
      hidf[(size_t)((m*2+0)*4+kt2)*512 + (row+lgrp)*8 + jj2] = hi;
      hidf[(size_t)((m*2+1)*4+kt2)*512 + (row+lgrp)*8 + jj2] = (_Float16)(hv2 - (float)hi);
    }
  }
  __syncthreads();

  // ---- F2 ----
  half8 ah2[4], al2[4];
  #pragma unroll
  for (int kt=0;kt<4;kt++){
    ah2[kt] = *(const half8*)(hidf + (size_t)((m*2+0)*4+kt)*512 + l*8);
    al2[kt] = *(const half8*)(hidf + (size_t)((m*2+1)*4+kt)*512 + l*8);
  }
  #pragma unroll
  for (int t2=0;t2<2;t2++){
    const int nt = n0 + t2;
    f32x4 acc = zc;
    #pragma unroll
    for (int kt=0;kt<4;kt++){
      const half8 bb = *(const half8*)(F2frag + (size_t)((nt*4+kt)*64 + l)*8);
      acc = __builtin_amdgcn_mfma_f32_16x16x32_f16(ah2[kt], bb, acc, 0, 0, 0);
      acc = __builtin_amdgcn_mfma_f32_16x16x32_f16(al2[kt], bb, acc, 0, 0, 0);
    }
    const int j = nt*16 + ccol;
    const float bias = f2[j];
    const int kt2 = j >> 5, lgrp = 16*((j>>3)&3), jj2 = j & 7;
    #pragma unroll
    for (int reg=0;reg<4;reg++){
      const int row = (l>>4)*4 + reg;
      const int rowg = m*16 + row;
      const float fv = fmaxf(acc[reg] + bias, 0.f) * okv[rowg];
      fus[rowg*129 + j] = fv;
      const _Float16 hi = (_Float16)fv;
      fusf[(size_t)((m*2+0)*4+kt2)*512 + (row+lgrp)*8 + jj2] = hi;
      fusf[(size_t)((m*2+1)*4+kt2)*512 + (row+lgrp)*8 + jj2] = (_Float16)(fv - (float)hi);
    }
  }
  __syncthreads();

  // ---- mean ----
  if (tid < H_){
    float s = 0.f;
    #pragma unroll 8
    for (int r=0;r<P_;r++) s += fus[r*129 + tid];
    meansh[tid] = s * rcpf(nvp[0]);
  }
  __syncthreads();

  // ---- A1 scores ----
  half8 af[4], alf[4], amh[4], aml[4];
  #pragma unroll
  for (int kt=0;kt<4;kt++){
    af[kt]  = *(const half8*)(fusf + (size_t)((m*2+0)*4+kt)*512 + l*8);
    alf[kt] = *(const half8*)(fusf + (size_t)((m*2+1)*4+kt)*512 + l*8);
    #pragma unroll
    for (int jj=0;jj<8;jj++){
      const float mv = meansh[kt*32 + 8*(l>>4) + jj];
      const _Float16 hi = (_Float16)mv;
      amh[kt][jj] = hi;
      aml[kt][jj] = (_Float16)(mv - (float)hi);
    }
  }
  float vsum[4] = {0.f,0.f,0.f,0.f};
  #pragma unroll
  for (int t2=0;t2<2;t2++){
    const int nt = n0 + t2;
    f32x4 acc = zc;
    #pragma unroll
    for (int kt=0;kt<4;kt++){
      const half8 bb = *(const half8*)(A1frag + (size_t)((nt*8+kt)*64 + l)*8);
      acc = __builtin_amdgcn_mfma_f32_16x16x32_f16(af[kt],  bb, acc, 0, 0, 0);
      acc = __builtin_amdgcn_mfma_f32_16x16x32_f16(alf[kt], bb, acc, 0, 0, 0);
    }
    #pragma unroll
    for (int kt=0;kt<4;kt++){
      const half8 bb = *(const half8*)(A1frag + (size_t)((nt*8+4+kt)*64 + l)*8);
      acc = __builtin_amdgcn_mfma_f32_16x16x32_f16(amh[kt], bb, acc, 0, 0, 0);
      acc = __builtin_amdgcn_mfma_f32_16x16x32_f16(aml[kt], bb, acc, 0, 0, 0);
    }
    const int j = nt*16 + ccol;
    const float b1 = a1[j], b2 = A2[j];
    #pragma unroll
    for (int reg=0;reg<4;reg++) vsum[reg] += fmaxf(acc[reg] + b1, 0.f) * b2;
  }
  #pragma unroll
  for (int off=1; off<16; off<<=1){
    #pragma unroll
    for (int reg=0;reg<4;reg++) vsum[reg] += __shfl_xor(vsum[reg], off, 64);
  }
  if (ccol == 0){
    #pragma unroll
    for (int reg=0;reg<4;reg++)
      sred[(m*16 + (l>>4)*4 + reg)*4 + (w&3)] = vsum[reg];
  }
  __syncthreads();

  if (tid < P_){
    float s = sred[tid*4+0]+sred[tid*4+1]+sred[tid*4+2]+sred[tid*4+3] + a2v[0];
    s = fmaxf(s, 0.f);
    s = (okv[tid] > 0.f) ? s : -1e9f;
    float mx = s;
    #pragma unroll
    for (int off=16; off>=1; off>>=1) mx = fmaxf(mx, __shfl_xor(mx, off, 32));
    const float e = (okv[tid] > 0.f) ? __expf(s - mx) : 0.f;
    float se = e;
    #pragma unroll
    for (int off=16; off>=1; off>>=1) se += __shfl_xor(se, off, 32);
    wgt[tid] = e * rcpf(fmaxf(se, 1e-9f));
  }
  __syncthreads();

  {
    const int rs = tid >> 7, j = tid & 127;
    float s = 0.f;
    #pragma unroll
    for (int r=rs*8; r<rs*8+8; ++r) s += wgt[r]*fus[r*129 + j];
    part[rs*128 + j] = s;
  }
  __syncthreads();
  if (tid < H_) out[b*H_ + tid] = part[0*128+tid]+part[1*128+tid]+part[2*128+tid]+part[3*128+tid];
}

extern "C" void kernel_launch(void* const* d_in, const int* in_sizes, int n_in,
                              void* d_out, int out_size, void* d_ws, size_t ws_size,
                              hipStream_t stream) {
  const float* rel   = (const float*)d_in[1];
  const float* pvx   = (const float*)d_in[2];
  const float* pvy   = (const float*)d_in[3];
  const float* pax   = (const float*)d_in[4];
  const float* pay   = (const float*)d_in[5];
  const int*   pmask = (const int*)  d_in[6];
  const float* W_sp  = (const float*)d_in[7];
  const float* b_sp  = (const float*)d_in[8];
  const float* W_st  = (const float*)d_in[9];
  const float* b_st  = (const float*)d_in[10];
  const float* Wih_t = (const float*)d_in[11];
  const float* Whh_t = (const float*)d_in[12];
  const float* bih_t = (const float*)d_in[13];
  const float* bhh_t = (const float*)d_in[14];
  const float* Wih_s = (const float*)d_in[15];
  const float* Whh_s = (const float*)d_in[16];
  const float* bih_s = (const float*)d_in[17];
  const float* bhh_s = (const float*)d_in[18];
  const float* A1    = (const float*)d_in[19];
  const float* a1    = (const float*)d_in[20];
  const float* A2    = (const float*)d_in[21];
  const float* a2v   = (const float*)d_in[22];
  const float* F1    = (const float*)d_in[23];
  const float* f1    = (const float*)d_in[24];
  const float* F2    = (const float*)d_in[25];
  const float* f2    = (const float*)d_in[26];

  float* ws = (float*)d_ws;
  size_t off = 0;
  _Float16* Bxfrag = (_Float16*)(ws + off); off += 16384;   // 32768 f16
  _Float16* F1frag = (_Float16*)(ws + off); off += 16384;   // 32768 f16
  _Float16* F2frag = (_Float16*)(ws + off); off += 8192;    // 16384 f16
  _Float16* A1frag = (_Float16*)(ws + off); off += 16384;   // 32768 f16
  float* h_t    = ws + off; off += (size_t)N_*H_;
  float* h_s    = ws + off; off += (size_t)N_*H_;

  hipLaunchKernelGGL(prep_kernel, dim3(32), dim3(256), 0, stream,
      W_sp, b_sp, W_st, b_st, Wih_t, bih_t, bhh_t,
      Wih_s, bih_s, bhh_s, F1, F2, A1,
      Bxfrag, F1frag, F2frag, A1frag);

  hipLaunchKernelGGL(lstm_kernel, dim3(N_/8, 2), dim3(512), 0, stream,
      rel, pvx, pvy, pax, pay, pmask,
      Whh_t, Whh_s, Bxfrag, h_t, h_s);

  const int head_lds = 71680;
  hipFuncSetAttribute((const void*)head_kernel,
                      hipFuncAttributeMaxDynamicSharedMemorySize, head_lds);
  hipLaunchKernelGGL(head_kernel, dim3(B_), dim3(512), head_lds, stream,
      h_t, h_s, pmask, F1frag, f1, F2frag, f2, A1frag, a1, A2, a2v,
      (float*)d_out);
}

// Round 15
// 67.897 us; speedup vs baseline: 1.1088x; 1.1088x over previous
//
#include <hip/hip_runtime.h>

#define T_ 64
#define B_ 32
#define P_ 32
#define N_ 1024
#define H_ 128
#define G_ 512   // 4*H

typedef __attribute__((ext_vector_type(8))) _Float16 half8;
typedef __attribute__((ext_vector_type(4))) float f32x4;

__device__ __forceinline__ float rcpf(float x){ return __builtin_amdgcn_rcpf(x); }
__device__ __forceinline__ float sigm(float x){ return rcpf(1.f+__expf(-x)); }
__device__ __forceinline__ float tanh_fast(float x){ return 1.f - 2.f*rcpf(__expf(2.f*x)+1.f); }

// ---------------- Kernel 0: prep (96 parallel blocks) ----------------
// blk 0-7  : Bx fragments
// blk 8-71 : Whh fragments (one (L,w,n) tile per block, LDS-staged, coalesced)
// blk 72-95: F1/F2/A1 B-fragment builders (8 n-tiles each), f16
__global__ __launch_bounds__(256) void prep_kernel(
    const float* __restrict__ W_sp, const float* __restrict__ b_sp,
    const float* __restrict__ W_st, const float* __restrict__ b_st,
    const float* __restrict__ Wih_t, const float* __restrict__ Whh_t,
    const float* __restrict__ bih_t, const float* __restrict__ bhh_t,
    const float* __restrict__ Wih_s, const float* __restrict__ Whh_s,
    const float* __restrict__ bih_s, const float* __restrict__ bhh_s,
    const float* __restrict__ F1, const float* __restrict__ F2,
    const float* __restrict__ A1,
    _Float16* __restrict__ Wfrag, _Float16* __restrict__ Bxfrag,
    _Float16* __restrict__ F1frag, _Float16* __restrict__ F2frag,
    _Float16* __restrict__ A1frag)
{
  __shared__ float Wl[128][129];       // 66KB staging
  __shared__ float spw[512];
  __shared__ float bsm[128];
  __shared__ float prt[128][8];

  const int tid = threadIdx.x;
  const int blk = blockIdx.x;

  if (blk < 8) {
    const int L = blk >> 2, q = blk & 3;
    const int g0 = q*128;
    const float* Wih = L ? Wih_s : Wih_t;
    {
      unsigned int* Bz = (unsigned int*)Bxfrag;
      for (int i = tid; i < 2048; i += 256){
        const int wv = i >> 8, word = i & 255;
        Bz[((L*8+wv)*4+q)*256 + word] = 0u;
      }
    }
    if (L == 0){
      if (tid < 256) spw[tid] = W_sp[tid];
      if (tid < 128) bsm[tid] = b_sp[tid];
    } else {
      spw[tid] = W_st[tid]; spw[256+tid] = W_st[256+tid];
      if (tid < 128) bsm[tid] = b_st[tid];
    }
    for (int idx = tid; idx < 4096; idx += 256){
      const int r = idx >> 5, c4 = idx & 31;
      const float4 v = *(const float4*)(Wih + (size_t)(g0+r)*H_ + c4*4);
      Wl[r][c4*4+0]=v.x; Wl[r][c4*4+1]=v.y; Wl[r][c4*4+2]=v.z; Wl[r][c4*4+3]=v.w;
    }
    __syncthreads();
    const int g_l = tid & 127, half = tid >> 7, e0 = half*64;
    float a0=0.f,a1v=0.f,a2=0.f,a3=0.f,ab=0.f;
    if (L == 0){
      for (int e=e0; e<e0+64; ++e){
        const float wv = Wl[g_l][e];
        a0 += wv*spw[e*2]; a1v += wv*spw[e*2+1]; ab += wv*bsm[e];
      }
    } else {
      for (int e=e0; e<e0+64; ++e){
        const float wv = Wl[g_l][e];
        a0 += wv*spw[e*4]; a1v += wv*spw[e*4+1]; a2 += wv*spw[e*4+2]; a3 += wv*spw[e*4+3];
        ab += wv*bsm[e];
      }
    }
    if (half == 1){ prt[g_l][0]=a0; prt[g_l][1]=a1v; prt[g_l][2]=a2; prt[g_l][3]=a3; prt[g_l][4]=ab; }
    __syncthreads();
    if (half == 0){
      a0 += prt[g_l][0]; a1v += prt[g_l][1]; a2 += prt[g_l][2]; a3 += prt[g_l][3]; ab += prt[g_l][4];
      const int g = g0 + g_l;
      const float bsum = ab + (L ? bih_s[g] : bih_t[g]) + (L ? bhh_s[g] : bhh_t[g]);
      const int wv = g_l >> 4, lane = g_l & 15;
      _Float16* dst = Bxfrag + (size_t)(((L*8+wv)*4+q)*64 + lane)*8;
      if (L == 0){
        dst[0]=(_Float16)a0; dst[1]=(_Float16)a1v; dst[2]=(_Float16)0.f; dst[3]=(_Float16)0.f;
      } else {
        dst[0]=(_Float16)a0; dst[1]=(_Float16)a1v; dst[2]=(_Float16)a2; dst[3]=(_Float16)a3;
      }
      const _Float16 bh = (_Float16)bsum;
      dst[4]=bh; dst[5]=(_Float16)(bsum-(float)bh);
    }
  } else if (blk < 72) {
    const int tb = blk - 8;            // 0..63
    const int L  = tb >> 5;
    const float* Whh = L ? Whh_s : Whh_t;
    const int g0 = (tb & 3)*128 + ((tb>>2)&7)*16;   // n*128 + w*16
    #pragma unroll
    for (int i=0;i<8;i++){
      const int fidx = tid + i*256;     // 0..2047
      const int r = fidx >> 7, c = fidx & 127;
      Wl[r][c] = Whh[(size_t)(g0+r)*H_ + c];
    }
    __syncthreads();
    const int l = tid & 63, t = tid >> 6;
    const int rr = l & 15, kb = t*32 + 8*(l>>4);
    half8 v;
    #pragma unroll
    for (int j=0;j<8;j++) v[j] = (_Float16)Wl[rr][kb+j];
    *(half8*)(Wfrag + (size_t)((tb*4 + t)*64 + l)*8) = v;
  } else {
    // B-fragment builders for head matrices
    const int fb = blk - 72;            // 0..23
    const int btype = fb >> 3;          // 0=F1, 1=F2, 2=A1
    const int nt = fb & 7;
    const float* src = (btype==0) ? F1 : (btype==1) ? F2 : A1;
    _Float16* dstf   = (btype==0) ? F1frag : (btype==1) ? F2frag : A1frag;
    const int K = (btype==1) ? 128 : 256;
    float* S = &Wl[0][0];               // staging, stride 257
    const int nf4 = 16*K/4;
    for (int i = tid; i < nf4; i += 256){
      const int r = i / (K/4), c4 = i % (K/4);
      const float4 v = *(const float4*)(src + (size_t)(nt*16+r)*K + c4*4);
      S[r*257 + c4*4+0]=v.x; S[r*257 + c4*4+1]=v.y;
      S[r*257 + c4*4+2]=v.z; S[r*257 + c4*4+3]=v.w;
    }
    __syncthreads();
    const int nkt = K/32;
    for (int s = tid; s < nkt*64; s += 256){
      const int kt = s >> 6, l = s & 63;
      half8 v;
      #pragma unroll
      for (int jj=0;jj<8;jj++)
        v[jj] = (_Float16)S[(l&15)*257 + kt*32 + 8*(l>>4) + jj];
      *(half8*)(dstf + (size_t)((nt*nkt + kt)*64 + l)*8) = v;
    }
  }
}

// ---------------- Kernel 1: both masked LSTMs, MFMA (R13 version) ----------------
__global__ __launch_bounds__(512) __attribute__((amdgpu_waves_per_eu(2,2)))
void lstm_kernel(
    const float* __restrict__ rel, const float* __restrict__ pvx,
    const float* __restrict__ pvy, const float* __restrict__ pax,
    const float* __restrict__ pay, const int* __restrict__ maskI,
    const _Float16* __restrict__ Wfrag, const _Float16* __restrict__ Bxfrag,
    float* __restrict__ h_t_out, float* __restrict__ h_s_out)
{
  __shared__ _Float16 hA[2][4][64][8] __align__(16);   // h f16, dbuf, 8KB
  __shared__ _Float16 axf[T_][16][8] __align__(16);    // x A-frags, 16KB
  __shared__ _Float16 zslot[8] __align__(16);
  __shared__ unsigned int ml[T_];

  const int lstm = blockIdx.y;
  const int tid  = threadIdx.x;
  const int w    = tid >> 6;
  const int l    = tid & 63;
  const int n0   = blockIdx.x * 8;
  const int u    = w*16 + (l & 15);
  const int kt_u = u >> 5;

  half8 bw[4][4], bx[4];
  #pragma unroll
  for (int n=0;n<4;n++){
    #pragma unroll
    for (int t=0;t<4;t++){
      const int base = ((((lstm*8 + w)*4 + n)*4 + t)*64 + l)*8;
      bw[n][t] = *(const half8*)(Wfrag + base);
    }
    bx[n] = *(const half8*)(Bxfrag + (((lstm*8 + w)*4 + n)*64 + l)*8);
  }

  {
    const int t = tid >> 3, r = tid & 7;
    const int n = n0 + r, b = n >> 5, p = n & 31;
    float x0,x1,x2,x3;
    if (lstm == 0){
      x0 = rel[(t*B_+b)*64 + p]; x1 = rel[(t*B_+b)*64 + 32 + p];
      x2 = 0.f; x3 = 0.f;
    } else {
      const int i0 = t*N_ + n;
      x0 = pvx[i0]; x1 = pvy[i0]; x2 = pax[i0]; x3 = pay[i0];
    }
    half8 v;
    v[0]=(_Float16)x0; v[1]=(_Float16)x1; v[2]=(_Float16)x2; v[3]=(_Float16)x3;
    v[4]=(_Float16)1.f; v[5]=(_Float16)1.f; v[6]=(_Float16)0.f; v[7]=(_Float16)0.f;
    *(half8*)&axf[t][r][0] = v;
    half8 zz;
    #pragma unroll
    for (int q=0;q<8;q++) zz[q]=(_Float16)0.f;
    *(half8*)&axf[t][8+r][0] = zz;
    if (tid == 0) *(half8*)&zslot[0] = zz;
    if (tid < T_){
      unsigned int mw = 0;
      for (int rr=0; rr<8; rr++) mw |= (maskI[tid*N_ + n0 + rr] > 0) ? (1u<<rr) : 0u;
      ml[tid] = mw;
    }
  }
  {
    unsigned int* hz = (unsigned int*)&hA[0][0][0][0];
    #pragma unroll
    for (int i=0;i<4;i++) hz[tid + i*512] = 0u;
  }

  const int halfw = l >> 5;
  const int rbase = ((l & 31) >> 4)*4 + 2*halfw;
  const int lpp0  = rbase + 16*((u >> 3) & 3);
  const int hoff0 = kt_u*512 + lpp0*8 + (u & 7);
  const int hoff1 = hoff0 + 8;
  _Float16* hbase = &hA[0][0][0][0];
  const _Float16* axp_base = (l < 16) ? &axf[0][l][0] : &zslot[0];
  const int ax_stride = (l < 16) ? 128 : 0;

  float cc0 = 0.f, cc1 = 0.f;
  _Float16 rh0 = (_Float16)0.f, rh1 = (_Float16)0.f;
  __syncthreads();

  const f32x4 zc = {0.f, 0.f, 0.f, 0.f};
  #pragma unroll 2
  for (int t=0; t<T_; ++t){
    const int cur = t & 1, nxt = cur ^ 1;
    const unsigned int mw = ml[t];

    const half8 ax = *(const half8*)(axp_base + t*ax_stride);
    f32x4 acc[4];
    #pragma unroll
    for (int n=0;n<4;n++)
      acc[n] = __builtin_amdgcn_mfma_f32_16x16x32_f16(ax, bx[n], zc, 0, 0, 0);

    half8 ah[4];
    #pragma unroll
    for (int kt=0;kt<4;kt++) ah[kt] = *(const half8*)&hA[cur][kt][l][0];

    #pragma unroll
    for (int kt=0;kt<4;kt++)
      #pragma unroll
      for (int n=0;n<4;n++)
        acc[n] = __builtin_amdgcn_mfma_f32_16x16x32_f16(ah[kt], bw[n][kt], acc[n], 0, 0, 0);

    float g0[4], g1[4];
    #pragma unroll
    for (int n=0;n<4;n++){
      const float s2 = __shfl_xor(acc[n][2], 32, 64);
      const float s3 = __shfl_xor(acc[n][3], 32, 64);
      g0[n] = halfw ? s2 : acc[n][0];
      g1[n] = halfw ? s3 : acc[n][1];
    }

    {
      const float cn = sigm(g0[1])*cc0 + sigm(g0[0])*tanh_fast(g0[2]);
      const float hn = sigm(g0[3])*tanh_fast(cn);
      const int mb = (mw >> rbase) & 1;
      cc0 = mb ? cn : cc0;
      rh0 = mb ? (_Float16)hn : rh0;
      hbase[nxt*2048 + hoff0] = rh0;
    }
    {
      const float cn = sigm(g1[1])*cc1 + sigm(g1[0])*tanh_fast(g1[2]);
      const float hn = sigm(g1[3])*tanh_fast(cn);
      const int mb = (mw >> (rbase+1)) & 1;
      cc1 = mb ? cn : cc1;
      rh1 = mb ? (_Float16)hn : rh1;
      hbase[nxt*2048 + hoff1] = rh1;
    }
    __syncthreads();
  }

  float* hout = lstm ? h_s_out : h_t_out;
  hout[(n0 + rbase    )*H_ + u] = (float)rh0;
  hout[(n0 + rbase + 1)*H_ + u] = (float)rh1;
}

// ---------------- Kernel 2: MFMA head (R13 version) ----------------
__global__ __launch_bounds__(512) void head_kernel(
    const float* __restrict__ h_t, const float* __restrict__ h_s,
    const int* __restrict__ maskI,
    const _Float16* __restrict__ F1frag, const float* __restrict__ f1,
    const _Float16* __restrict__ F2frag, const float* __restrict__ f2,
    const _Float16* __restrict__ A1frag, const float* __restrict__ a1,
    const float* __restrict__ A2, const float* __restrict__ a2v,
    float* __restrict__ out)
{
  extern __shared__ char hsm[];
  _Float16* combf = (_Float16*)hsm;              // [2m][2hl][8kt][64][8] 32768B
  _Float16* fusf  = (_Float16*)hsm;              // alias: 16384B
  _Float16* hidf  = (_Float16*)(hsm + 32768);    // 16384B
  float* fus      = (float*)(hsm + 49152);       // [32][129] 16512B
  float* meansh   = (float*)(hsm + 65664);       // 128
  float* okcnt    = (float*)(hsm + 66176);       // 512
  float* okv      = (float*)(hsm + 68224);       // 32
  float* sred     = (float*)(hsm + 68352);       // 32x4
  float* wgt      = (float*)(hsm + 68864);       // 32
  float* part     = (float*)(hsm + 68992);       // 4x128
  float* nvp      = (float*)(hsm + 71040);       // 1

  const int b = blockIdx.x, tid = threadIdx.x;
  const int w = tid >> 6, l = tid & 63;
  const int m = w >> 2;
  const int n0 = (w & 3) * 2;
  const int ccol = l & 15;

  #pragma unroll
  for (int it = 0; it < 4; ++it){
    const int slot = tid + it*512;
    const int r = slot >> 6, c4 = slot & 63;
    const float4 v = (c4 < 32)
      ? *(const float4*)(h_t + (size_t)(b*P_+r)*H_ + c4*4)
      : *(const float4*)(h_s + (size_t)(b*P_+r)*H_ + (c4-32)*4);
    const int mm = r >> 4, rl = r & 15;
    float vv[4] = {v.x, v.y, v.z, v.w};
    #pragma unroll
    for (int e=0;e<4;e++){
      const int k = c4*4 + e;
      const int lane = rl + 16*((k>>3)&3);
      const int jj = k & 7, kt = k >> 5;
      const _Float16 hi = (_Float16)vv[e];
      const _Float16 lo = (_Float16)(vv[e] - (float)hi);
      combf[(size_t)((mm*2+0)*8+kt)*512 + lane*8 + jj] = hi;
      combf[(size_t)((mm*2+1)*8+kt)*512 + lane*8 + jj] = lo;
    }
  }
  {
    const int p = tid >> 4, tt = tid & 15;
    int c = 0;
    #pragma unroll
    for (int q2=0;q2<4;q2++) c += (maskI[(tt*4+q2)*N_ + b*P_ + p] > 0);
    okcnt[p*16+tt] = (float)c;
  }
  __syncthreads();

  if (tid < 32){
    float c = 0.f;
    #pragma unroll
    for (int q2=0;q2<16;q2++) c += okcnt[tid*16+q2];
    const float ok = (c >= 2.f) ? 1.f : 0.f;
    okv[tid] = ok;
    float nvv = ok;
    #pragma unroll
    for (int off=16; off>=1; off>>=1) nvv += __shfl_xor(nvv, off, 32);
    if (tid == 0) nvp[0] = fmaxf(nvv, 1.f);
  }

  const f32x4 zc = {0.f,0.f,0.f,0.f};

  // ---- F1 ----
  half8 ah[8], al[8];
  #pragma unroll
  for (int kt=0;kt<8;kt++){
    ah[kt] = *(const half8*)(combf + (size_t)((m*2+0)*8+kt)*512 + l*8);
    al[kt] = *(const half8*)(combf + (size_t)((m*2+1)*8+kt)*512 + l*8);
  }
  float hval[2][4];
  #pragma unroll
  for (int t2=0;t2<2;t2++){
    const int nt = n0 + t2;
    f32x4 acc = zc;
    #pragma unroll
    for (int kt=0;kt<8;kt++){
      const half8 bb = *(const half8*)(F1frag + (size_t)((nt*8+kt)*64 + l)*8);
      acc = __builtin_amdgcn_mfma_f32_16x16x32_f16(ah[kt], bb, acc, 0, 0, 0);
      acc = __builtin_amdgcn_mfma_f32_16x16x32_f16(al[kt], bb, acc, 0, 0, 0);
    }
    const float bias = f1[nt*16 + ccol];
    #pragma unroll
    for (int reg=0;reg<4;reg++) hval[t2][reg] = fmaxf(acc[reg] + bias, 0.f);
  }
  #pragma unroll
  for (int t2=0;t2<2;t2++){
    const int jb = (n0+t2)*16 + ccol;
    const int kt2 = jb >> 5, lgrp = 16*((jb>>3)&3), jj2 = jb & 7;
    #pragma unroll
    for (int reg=0;reg<4;reg++){
      const int row = (l>>4)*4 + reg;
      const float hv2 = hval[t2][reg];
      const _Float16 hi = (_Float16)hv2;
      hidf[(size_t)((m*2+0)*4+kt2)*512 + (row+lgrp)*8 + jj2] = hi;
      hidf[(size_t)((m*2+1)*4+kt2)*512 + (row+lgrp)*8 + jj2] = (_Float16)(hv2 - (float)hi);
    }
  }
  __syncthreads();

  // ---- F2 ----
  half8 ah2[4], al2[4];
  #pragma unroll
  for (int kt=0;kt<4;kt++){
    ah2[kt] = *(const half8*)(hidf + (size_t)((m*2+0)*4+kt)*512 + l*8);
    al2[kt] = *(const half8*)(hidf + (size_t)((m*2+1)*4+kt)*512 + l*8);
  }
  #pragma unroll
  for (int t2=0;t2<2;t2++){
    const int nt = n0 + t2;
    f32x4 acc = zc;
    #pragma unroll
    for (int kt=0;kt<4;kt++){
      const half8 bb = *(const half8*)(F2frag + (size_t)((nt*4+kt)*64 + l)*8);
      acc = __builtin_amdgcn_mfma_f32_16x16x32_f16(ah2[kt], bb, acc, 0, 0, 0);
      acc = __builtin_amdgcn_mfma_f32_16x16x32_f16(al2[kt], bb, acc, 0, 0, 0);
    }
    const int j = nt*16 + ccol;
    const float bias = f2[j];
    const int kt2 = j >> 5, lgrp = 16*((j>>3)&3), jj2 = j & 7;
    #pragma unroll
    for (int reg=0;reg<4;reg++){
      const int row = (l>>4)*4 + reg;
      const int rowg = m*16 + row;
      const float fv = fmaxf(acc[reg] + bias, 0.f) * okv[rowg];
      fus[rowg*129 + j] = fv;
      const _Float16 hi = (_Float16)fv;
      fusf[(size_t)((m*2+0)*4+kt2)*512 + (row+lgrp)*8 + jj2] = hi;
      fusf[(size_t)((m*2+1)*4+kt2)*512 + (row+lgrp)*8 + jj2] = (_Float16)(fv - (float)hi);
    }
  }
  __syncthreads();

  // ---- mean ----
  if (tid < H_){
    float s = 0.f;
    #pragma unroll 8
    for (int r=0;r<P_;r++) s += fus[r*129 + tid];
    meansh[tid] = s * rcpf(nvp[0]);
  }
  __syncthreads();

  // ---- A1 scores ----
  half8 af[4], alf[4], amh[4], aml[4];
  #pragma unroll
  for (int kt=0;kt<4;kt++){
    af[kt]  = *(const half8*)(fusf + (size_t)((m*2+0)*4+kt)*512 + l*8);
    alf[kt] = *(const half8*)(fusf + (size_t)((m*2+1)*4+kt)*512 + l*8);
    #pragma unroll
    for (int jj=0;jj<8;jj++){
      const float mv = meansh[kt*32 + 8*(l>>4) + jj];
      const _Float16 hi = (_Float16)mv;
      amh[kt][jj] = hi;
      aml[kt][jj] = (_Float16)(mv - (float)hi);
    }
  }
  float vsum[4] = {0.f,0.f,0.f,0.f};
  #pragma unroll
  for (int t2=0;t2<2;t2++){
    const int nt = n0 + t2;
    f32x4 acc = zc;
    #pragma unroll
    for (int kt=0;kt<4;kt++){
      const half8 bb = *(const half8*)(A1frag + (size_t)((nt*8+kt)*64 + l)*8);
      acc = __builtin_amdgcn_mfma_f32_16x16x32_f16(af[kt],  bb, acc, 0, 0, 0);
      acc = __builtin_amdgcn_mfma_f32_16x16x32_f16(alf[kt], bb, acc, 0, 0, 0);
    }
    #pragma unroll
    for (int kt=0;kt<4;kt++){
      const half8 bb = *(const half8*)(A1frag + (size_t)((nt*8+4+kt)*64 + l)*8);
      acc = __builtin_amdgcn_mfma_f32_16x16x32_f16(amh[kt], bb, acc, 0, 0, 0);
      acc = __builtin_amdgcn_mfma_f32_16x16x32_f16(aml[kt], bb, acc, 0, 0, 0);
    }
    const int j = nt*16 + ccol;
    const float b1 = a1[j], b2 = A2[j];
    #pragma unroll
    for (int reg=0;reg<4;reg++) vsum[reg] += fmaxf(acc[reg] + b1, 0.f) * b2;
  }
  #pragma unroll
  for (int off=1; off<16; off<<=1){
    #pragma unroll
    for (int reg=0;reg<4;reg++) vsum[reg] += __shfl_xor(vsum[reg], off, 64);
  }
  if (ccol == 0){
    #pragma unroll
    for (int reg=0;reg<4;reg++)
      sred[(m*16 + (l>>4)*4 + reg)*4 + (w&3)] = vsum[reg];
  }
  __syncthreads();

  if (tid < P_){
    float s = sred[tid*4+0]+sred[tid*4+1]+sred[tid*4+2]+sred[tid*4+3] + a2v[0];
    s = fmaxf(s, 0.f);
    s = (okv[tid] > 0.f) ? s : -1e9f;
    float mx = s;
    #pragma unroll
    for (int off=16; off>=1; off>>=1) mx = fmaxf(mx, __shfl_xor(mx, off, 32));
    const float e = (okv[tid] > 0.f) ? __expf(s - mx) : 0.f;
    float se = e;
    #pragma unroll
    for (int off=16; off>=1; off>>=1) se += __shfl_xor(se, off, 32);
    wgt[tid] = e * rcpf(fmaxf(se, 1e-9f));
  }
  __syncthreads();

  {
    const int rs = tid >> 7, j = tid & 127;
    float s = 0.f;
    #pragma unroll
    for (int r=rs*8; r<rs*8+8; ++r) s += wgt[r]*fus[r*129 + j];
    part[rs*128 + j] = s;
  }
  __syncthreads();
  if (tid < H_) out[b*H_ + tid] = part[0*128+tid]+part[1*128+tid]+part[2*128+tid]+part[3*128+tid];
}

extern "C" void kernel_launch(void* const* d_in, const int* in_sizes, int n_in,
                              void* d_out, int out_size, void* d_ws, size_t ws_size,
                              hipStream_t stream) {
  const float* rel   = (const float*)d_in[1];
  const float* pvx   = (const float*)d_in[2];
  const float* pvy   = (const float*)d_in[3];
  const float* pax   = (const float*)d_in[4];
  const float* pay   = (const float*)d_in[5];
  const int*   pmask = (const int*)  d_in[6];
  const float* W_sp  = (const float*)d_in[7];
  const float* b_sp  = (const float*)d_in[8];
  const float* W_st  = (const float*)d_in[9];
  const float* b_st  = (const float*)d_in[10];
  const float* Wih_t = (const float*)d_in[11];
  const float* Whh_t = (const float*)d_in[12];
  const float* bih_t = (const float*)d_in[13];
  const float* bhh_t = (const float*)d_in[14];
  const float* Wih_s = (const float*)d_in[15];
  const float* Whh_s = (const float*)d_in[16];
  const float* bih_s = (const float*)d_in[17];
  const float* bhh_s = (const float*)d_in[18];
  const float* A1    = (const float*)d_in[19];
  const float* a1    = (const float*)d_in[20];
  const float* A2    = (const float*)d_in[21];
  const float* a2v   = (const float*)d_in[22];
  const float* F1    = (const float*)d_in[23];
  const float* f1    = (const float*)d_in[24];
  const float* F2    = (const float*)d_in[25];
  const float* f2    = (const float*)d_in[26];

  float* ws = (float*)d_ws;
  size_t off = 0;
  _Float16* Wfrag  = (_Float16*)(ws + off); off += 65536;   // 131072 f16
  _Float16* Bxfrag = (_Float16*)(ws + off); off += 16384;   // 32768 f16
  _Float16* F1frag = (_Float16*)(ws + off); off += 16384;   // 32768 f16
  _Float16* F2frag = (_Float16*)(ws + off); off += 8192;    // 16384 f16
  _Float16* A1frag = (_Float16*)(ws + off); off += 16384;   // 32768 f16
  float* h_t    = ws + off; off += (size_t)N_*H_;
  float* h_s    = ws + off; off += (size_t)N_*H_;

  hipLaunchKernelGGL(prep_kernel, dim3(96), dim3(256), 0, stream,
      W_sp, b_sp, W_st, b_st, Wih_t, Whh_t, bih_t, bhh_t,
      Wih_s, Whh_s, bih_s, bhh_s, F1, F2, A1,
      Wfrag, Bxfrag, F1frag, F2frag, A1frag);

  hipLaunchKernelGGL(lstm_kernel, dim3(N_/8, 2), dim3(512), 0, stream,
      rel, pvx, pvy, pax, pay, pmask,
      Wfrag, Bxfrag, h_t, h_s);

  const int head_lds = 71680;
  hipFuncSetAttribute((const void*)head_kernel,
                      hipFuncAttributeMaxDynamicSharedMemorySize, head_lds);
  hipLaunchKernelGGL(head_kernel, dim3(B_), dim3(512), head_lds, stream,
      h_t, h_s, pmask, F1frag, f1, F2frag, f2, A1frag, a1, A2, a2v,
      (float*)d_out);
}